// Round 3
// baseline (302.473 us; speedup 1.0000x reference)
//
#include <hip/hip_runtime.h>

// Problem constants (fixed by the reference's setup_inputs).
#define BATCH 8
#define CH    16
#define HH    512
#define WW    512
#define HW    (HH * WW)     // 262144

#define TILE  32            // output tile edge per block
#define RPAD  16            // halo radius staged in LDS
#define REGE  64            // staged region edge = TILE + 2*RPAD
#define NPX   4             // pixels per thread = TILE*TILE / 256
#define CG    2             // channels (planes) per group
#define NG    (CH / CG)     // 8 groups

// R3: global_load_lds staging (T3-lite schedule), channel-planar LDS.
//
// R2 post-mortem: register ping-pong prefetch asked the allocator to hold
// 128 VGPRs of staged data; it refused (VGPR_Count=92) and partially
// re-serialized the stage. Fix: stage via __builtin_amdgcn_global_load_lds
// width=16 -- zero VGPR footprint, no ds_write pass. One instr per wave
// writes 1 KB = 4 region rows of one channel plane (wave-uniform LDS base +
// lane*16; global source is per-lane). LDS is channel-PLANAR
// buf[2][CG][64][64] fp32 = 64 KB, double-buffered planes: per group g,
// phase = { issue stage(g+1 -> buf[(g+1)&1]); gather(g from buf[g&1]);
// __syncthreads() }. The barrier's vmcnt(0) drain lands AFTER the gather has
// covered the load latency; writing buf[(g+1)&1] is safe because the
// previous barrier retired gather(g-1) from that buffer on all waves.
// Prologue pre-issues groups 0 AND 1 (both buffers empty) under the
// per-pixel flow precompute, so phase 0 is pure gather.
//
// Staging source chunks: lane loads 16 B at off = gy*WW + x0r + (lane&15)*4
// with gy row-clamped. x0r is a multiple of 16 floats and 512 is a multiple
// of 4, so chunks are 16B-aligned and NEVER straddle an image row boundary:
// a chunk is either fully inside [0,511] in x (correct data, matching the
// old per-cell clamp semantics) or fully outside (offset-clamped to
// [0, HW-4] -> finite garbage). Garbage cells have nominal gx outside
// [0,511] and are never referenced by CLAMPED corner coords of non-fixup
// pixels; fixup-flagged pixels are recomputed from global afterwards (same
// thread stores both -> program order guarantees the final value).
//
// Kept from R1/R2: XCD-contiguous blockIdx swizzle (bijective, 2048%8==0;
// FETCH_SIZE 229MB -> 105MB), fbmask + fixup-recompute, mask folded into
// weights on UNCLIPPED floor coords (bit-exact vs reference).

typedef __attribute__((address_space(1))) const void global_cvoid;
typedef __attribute__((address_space(3))) void lds_void;

__device__ __forceinline__ void gll16(const float* g, float* l) {
    __builtin_amdgcn_global_load_lds((global_cvoid*)g, (lds_void*)l, 16, 0, 0);
}

// Issue staging for group g into buffer nb. Per wave: CG*4 = 8 instrs, each
// covering 4 rows of one plane. q = quad index 0..15 (rows q*4..q*4+3).
#define STAGE(g, nb) do {                                               \
    _Pragma("unroll")                                                   \
    for (int c_ = 0; c_ < CG; ++c_) {                                   \
        const float* pc_ = img + ib + (size_t)((g) * CG + c_) * HW;     \
        _Pragma("unroll")                                               \
        for (int k_ = 0; k_ < 4; ++k_) {                                \
            const int q_  = k_ * 4 + wv;          /* 0..15, wave-uniform */ \
            const int ry_ = q_ * 4 + sub;         /* this lane's row */  \
            const int gy_ = min(max(y0r + ry_, 0), HH - 1);             \
            const int off_ = min(max(gy_ * WW + xch, 0), HW - 4);       \
            gll16(pc_ + off_, &buf[nb][c_][q_ * 4][0]);                 \
        }                                                               \
    }                                                                   \
} while (0)

#define GATHER(g, cb) do {                                              \
    _Pragma("unroll")                                                   \
    for (int c_ = 0; c_ < CG; ++c_) {                                   \
        const float* pl_ = &buf[cb][c_][0][0];                          \
        float* o0_ = out + ib + (size_t)((g) * CG + c_) * HW;           \
        _Pragma("unroll")                                               \
        for (int p_ = 0; p_ < NPX; ++p_) {                              \
            const int l_   = lidx[p_];                                  \
            const int dx_  = dxv[p_];                                   \
            const int dyo_ = dyov[p_];                                  \
            const float v00 = pl_[l_];                                  \
            const float v01 = pl_[l_ + dx_];                            \
            const float v10 = pl_[l_ + dyo_];                           \
            const float v11 = pl_[l_ + dx_ + dyo_];                     \
            o0_[obase[p_]] = w00[p_]*v00 + w01[p_]*v01                  \
                           + w10[p_]*v10 + w11[p_]*v11;                 \
        }                                                               \
    }                                                                   \
} while (0)

__global__ __launch_bounds__(256) void warp_gll(
    const float* __restrict__ img,
    const float* __restrict__ flo,
    float* __restrict__ out)
{
    __shared__ float buf[2][CG][REGE][REGE];   // 64 KB -> 2 blocks/CU

    const int t   = threadIdx.x;
    const int bid = blockIdx.x;           // 0..2047
    const int tile = (bid & 7) * 256 + (bid >> 3);   // XCD-contiguous chunks
    const int b    = tile >> 8;
    const int ty   = (tile >> 4) & 15;
    const int tx   = tile & 15;
    const int xb   = tx * TILE;
    const int yb   = ty * TILE;
    const int x0r  = xb - RPAD;           // region origin (may be negative)
    const int y0r  = yb - RPAD;

    // ---- staging geometry (channel-invariant) ----
    const int lane = t & 63;
    const int wv   = t >> 6;              // wave id 0..3
    const int sub  = lane >> 4;           // row-within-quad 0..3
    const int xch  = x0r + (lane & 15) * 4;  // this lane's 4-float x chunk
    const size_t ib = (size_t)b * CH * HW;

    // ---- pre-issue staging for groups 0 and 1 (both buffers empty) ----
    STAGE(0, 0);
    STAGE(1, 1);

    // ---- per-pixel precompute (channel-invariant); hides staging latency --
    float w00[NPX], w01[NPX], w10[NPX], w11[NPX];
    int   lidx[NPX], dxv[NPX], dyov[NPX], obase[NPX];
    int   fbmask = 0;

    const float* fbp = flo + (size_t)b * 2 * HW;

#pragma unroll
    for (int p = 0; p < NPX; ++p) {
        const int pix = p * 256 + t;      // 0..1023 within tile
        const int row = pix >> 5;
        const int col = pix & 31;
        const int h   = yb + row;
        const int w   = xb + col;
        const int hw  = h * WW + w;
        obase[p] = hw;

        const float fx = fbp[hw];         // coalesced
        const float fy = fbp[HW + hw];
        const float gx = (float)w + fx;
        const float gy = (float)h + fy;

        const float x0f = floorf(gx), y0f = floorf(gy);
        const float wx1 = gx - x0f, wx0 = 1.0f - wx1;
        const float wy1 = gy - y0f, wy0 = 1.0f - wy1;

        const bool vx0 = (x0f >= 0.0f)        && (x0f <= (float)(WW - 1));
        const bool vx1 = (x0f + 1.0f >= 0.0f) && (x0f + 1.0f <= (float)(WW - 1));
        const bool vy0 = (y0f >= 0.0f)        && (y0f <= (float)(HH - 1));
        const bool vy1 = (y0f + 1.0f >= 0.0f) && (y0f + 1.0f <= (float)(HH - 1));

        float a00 = wx0 * wy0 * ((vx0 && vy0) ? 1.0f : 0.0f);
        float a01 = wx1 * wy0 * ((vx1 && vy0) ? 1.0f : 0.0f);
        float a10 = wx0 * wy1 * ((vx0 && vy1) ? 1.0f : 0.0f);
        float a11 = wx1 * wy1 * ((vx1 && vy1) ? 1.0f : 0.0f);

        const float msum = a00 + a01 + a10 + a11;
        const float mask = (msum < 0.9999f) ? 0.0f : 1.0f;
        w00[p] = a00 * mask; w01[p] = a01 * mask;
        w10[p] = a10 * mask; w11[p] = a11 * mask;

        const int x0 = min(max((int)x0f, 0), WW - 1);
        const int x1 = min(max((int)x0f + 1, 0), WW - 1);
        const int y0 = min(max((int)y0f, 0), HH - 1);
        const int y1 = min(max((int)y0f + 1, 0), HH - 1);

        const int dx = x1 - x0;           // 0 or 1
        const int dy = y1 - y0;
        dxv[p]  = dx;
        dyov[p] = dy * REGE;

        const int xl = x0 - x0r;          // region-local (may be out of range)
        const int yl = y0 - y0r;
        if (!((xl >= 0) && (xl + dx <= REGE - 1) &&
              (yl >= 0) && (yl + dy <= REGE - 1)))
            fbmask |= (1 << p);
        // Clamp to [0, REGE-2]: exact for every in-region pixel, safe-finite
        // for fallback pixels (overwritten by fixup).
        lidx[p] = min(max(yl, 0), REGE - 2) * REGE + min(max(xl, 0), REGE - 2);
    }

    __syncthreads();                      // groups 0,1 staged (vmcnt drained)

    // ---- main loop: stage(g+1) || gather(g), one barrier per group ----
    GATHER(0, 0);
    __syncthreads();
    STAGE(2, 0);  GATHER(1, 1);  __syncthreads();
    STAGE(3, 1);  GATHER(2, 0);  __syncthreads();
    STAGE(4, 0);  GATHER(3, 1);  __syncthreads();
    STAGE(5, 1);  GATHER(4, 0);  __syncthreads();
    STAGE(6, 0);  GATHER(5, 1);  __syncthreads();
    STAGE(7, 1);  GATHER(6, 0);  __syncthreads();
    GATHER(7, 1);                         // last group: no further staging

    // ---- fixup: redo fallback pixels from global (all 16 channels) ----
    // Rare path. Recomputes weights/indices from a flow reload (L2-hot).
    if (fbmask) {
#pragma unroll
        for (int p = 0; p < NPX; ++p) {
            if (!(fbmask & (1 << p))) continue;
            const int pix = p * 256 + t;
            const int row = pix >> 5;
            const int col = pix & 31;
            const int h   = yb + row;
            const int w   = xb + col;
            const int hw  = h * WW + w;

            const float fx = fbp[hw];
            const float fy = fbp[HW + hw];
            const float gx = (float)w + fx;
            const float gy = (float)h + fy;

            const float x0f = floorf(gx), y0f = floorf(gy);
            const float wx1 = gx - x0f, wx0 = 1.0f - wx1;
            const float wy1 = gy - y0f, wy0 = 1.0f - wy1;

            const bool vx0 = (x0f >= 0.0f)        && (x0f <= (float)(WW - 1));
            const bool vx1 = (x0f + 1.0f >= 0.0f) && (x0f + 1.0f <= (float)(WW - 1));
            const bool vy0 = (y0f >= 0.0f)        && (y0f <= (float)(HH - 1));
            const bool vy1 = (y0f + 1.0f >= 0.0f) && (y0f + 1.0f <= (float)(HH - 1));

            float a00 = wx0 * wy0 * ((vx0 && vy0) ? 1.0f : 0.0f);
            float a01 = wx1 * wy0 * ((vx1 && vy0) ? 1.0f : 0.0f);
            float a10 = wx0 * wy1 * ((vx0 && vy1) ? 1.0f : 0.0f);
            float a11 = wx1 * wy1 * ((vx1 && vy1) ? 1.0f : 0.0f);

            const float msum = a00 + a01 + a10 + a11;
            const float mask = (msum < 0.9999f) ? 0.0f : 1.0f;
            a00 *= mask; a01 *= mask; a10 *= mask; a11 *= mask;

            const int x0 = min(max((int)x0f, 0), WW - 1);
            const int x1 = min(max((int)x0f + 1, 0), WW - 1);
            const int y0 = min(max((int)y0f, 0), HH - 1);
            const int y1 = min(max((int)y0f + 1, 0), HH - 1);

            const int gA  = y0 * WW + x0;
            const int dx  = x1 - x0;
            const int dyo = (y1 - y0) * WW;

            const float* ic = img + ib;
            float*       oc = out + ib + hw;
            for (int c = 0; c < CH; ++c) {
                const float* pc = ic + (size_t)c * HW;
                const float v = a00 * pc[gA]
                              + a01 * pc[gA + dx]
                              + a10 * pc[gA + dyo]
                              + a11 * pc[gA + dx + dyo];
                oc[(size_t)c * HW] = v;
            }
        }
    }
}

extern "C" void kernel_launch(void* const* d_in, const int* in_sizes, int n_in,
                              void* d_out, int out_size, void* d_ws, size_t ws_size,
                              hipStream_t stream) {
    const float* img = (const float*)d_in[0];  // [8,16,512,512] fp32
    const float* flo = (const float*)d_in[1];  // [8,2,512,512] fp32
    float* out = (float*)d_out;                // [8,16,512,512] fp32

    const int blocks = BATCH * (HH / TILE) * (WW / TILE);  // 2048
    warp_gll<<<blocks, 256, 0, stream>>>(img, flo, out);
}

// Round 4
// 280.349 us; speedup vs baseline: 1.0789x; 1.0789x over previous
//
#include <hip/hip_runtime.h>

// Problem constants (fixed by the reference's setup_inputs).
#define BATCH 8
#define CH    16
#define HH    512
#define WW    512
#define HW    (HH * WW)     // 262144

#define TILE  32            // output tile edge per block
#define RPAD  16            // halo radius staged in LDS
#define REGE  64            // staged region edge = TILE + 2*RPAD
#define NPX   4             // pixels per thread = TILE*TILE / 256

// R4: m201-style counted-vmcnt pipeline (T3+T4 port).
//
// R0-R3 post-mortem: no pipe ever exceeded ~31% (HBM 25%, LDS ~20%, VALU
// 11%) -- the bound is the vmcnt(0)+lgkmcnt(0) drain __syncthreads() emits
// every phase, which drains the NEXT group's staging loads and the phase's
// stores with only 2 blocks/CU of cover. Fix per the m201 template:
//  * CG=1: one channel plane per group, 16 phases. buf[3][64][64] fp32 =
//    48 KB -> 3 blocks/CU (12 waves, was 8).
//  * Depth-3 staging: phase g = { GATHER(g, g%3); s_waitcnt vmcnt(4);
//    s_barrier; STAGE(g+3, g%3) }. The wait retires ONLY group g+1's 4
//    gll16 loads (issued two phases earlier -> 2 gather-phases of latency
//    cover); g+2/g+3's loads stay in flight ACROSS the barrier. Never
//    vmcnt(0) in the loop.
//  * Pure-gll vmcnt queue: per-phase results accumulate in registers
//    (res[16][4], +64 VGPR -- free: LDS caps occupancy at 3 waves/SIMD
//    which tolerates <=168 VGPR) and are stored in one coalesced burst at
//    the end, so the counted waits never depend on store retirement order.
//  * Flow loads hoisted BEFORE all gll (vmcnt queue is in-order: the
//    compiler's dependent-use wait for flow then drains only flow, not the
//    staging loads). An empty memory-clobber asm pins that order.
//
// Staging: __builtin_amdgcn_global_load_lds width=16. One instr per wave
// writes 1 KB = 4 rows of the plane (wave-uniform LDS base + lane*16;
// per-lane global source). 4 instrs/wave cover the 64x64 plane. Source
// chunks are 16B-aligned (x0r multiple of 16 floats) and never straddle an
// image row; fully-out-of-image chunks are offset-clamped -> finite garbage
// in cells no clamped corner of a non-fixup pixel can reference (fixup
// pixels are recomputed from global afterwards; same thread stores both ->
// program order guarantees the final value).
//
// Kept: XCD-contiguous blockIdx swizzle (bijective, 2048%8==0; FETCH_SIZE
// 229MB -> 105MB), fbmask + fixup-recompute, mask folded into weights on
// UNCLIPPED floor coords (bit-exact vs reference).

typedef __attribute__((address_space(1))) const void global_cvoid;
typedef __attribute__((address_space(3))) void lds_void;

__device__ __forceinline__ void gll16(const float* g, float* l) {
    __builtin_amdgcn_global_load_lds((global_cvoid*)g, (lds_void*)l, 16, 0, 0);
}

#define WAITVM(n) asm volatile("s_waitcnt vmcnt(" #n ")" ::: "memory")
#define BAR()     __builtin_amdgcn_s_barrier()

// Stage channel plane g into buffer nb: 4 gll16 per wave (quads k*4+wv).
#define STAGE(g, nb) do {                                               \
    const float* pc_ = img + ib + (size_t)(g) * HW;                     \
    _Pragma("unroll")                                                   \
    for (int k_ = 0; k_ < 4; ++k_) {                                    \
        gll16(pc_ + goff[k_], &buf[nb][(k_ * 4 + wv) * 4][0]);          \
    }                                                                   \
} while (0)

// Gather channel g from buffer cb into the register accumulator.
#define GATHER(g, cb) do {                                              \
    const float* pl_ = &buf[cb][0][0];                                  \
    _Pragma("unroll")                                                   \
    for (int p_ = 0; p_ < NPX; ++p_) {                                  \
        const int l_   = lidx[p_];                                      \
        const int dx_  = dxv[p_];                                       \
        const int dyo_ = dyov[p_];                                      \
        const float v00 = pl_[l_];                                      \
        const float v01 = pl_[l_ + dx_];                                \
        const float v10 = pl_[l_ + dyo_];                               \
        const float v11 = pl_[l_ + dx_ + dyo_];                         \
        res[g][p_] = w00[p_]*v00 + w01[p_]*v01                          \
                   + w10[p_]*v10 + w11[p_]*v11;                         \
    }                                                                   \
} while (0)

// Full phase: gather g, retire ONLY group g+1's staging loads, barrier,
// then refill the just-consumed buffer with group g+3.
#define PHASE(g) do {                                                   \
    GATHER(g, (g) % 3);                                                 \
    WAITVM(4);                                                          \
    BAR();                                                              \
    STAGE((g) + 3, (g) % 3);                                            \
} while (0)

__global__ __launch_bounds__(256, 3) void warp_cnt(
    const float* __restrict__ img,
    const float* __restrict__ flo,
    float* __restrict__ out)
{
    __shared__ float buf[3][REGE][REGE];   // 48 KB -> 3 blocks/CU

    const int t   = threadIdx.x;
    const int bid = blockIdx.x;           // 0..2047
    const int tile = (bid & 7) * 256 + (bid >> 3);   // XCD-contiguous chunks
    const int b    = tile >> 8;
    const int ty   = (tile >> 4) & 15;
    const int tx   = tile & 15;
    const int xb   = tx * TILE;
    const int yb   = ty * TILE;
    const int x0r  = xb - RPAD;           // region origin (may be negative)
    const int y0r  = yb - RPAD;

    // ---- staging geometry (channel-invariant) ----
    const int lane = t & 63;
    const int wv   = t >> 6;              // wave id 0..3 (wave-uniform)
    const int sub  = lane >> 4;           // row-within-quad 0..3
    const int xch  = x0r + (lane & 15) * 4;  // this lane's 4-float x chunk
    const size_t ib = (size_t)b * CH * HW;

    int goff[4];                          // per-lane staged global offsets
#pragma unroll
    for (int k = 0; k < 4; ++k) {
        const int q  = k * 4 + wv;        // quad 0..15
        const int ry = q * 4 + sub;       // this lane's region row 0..63
        const int gy = min(max(y0r + ry, 0), HH - 1);
        goff[k] = min(max(gy * WW + xch, 0), HW - 4);
    }

    // ---- flow loads FIRST (oldest in the in-order vmcnt queue) ----
    const float* fbp = flo + (size_t)b * 2 * HW;
    float fxv[NPX], fyv[NPX];
#pragma unroll
    for (int p = 0; p < NPX; ++p) {
        const int pix = p * 256 + t;
        const int hw  = (yb + (pix >> 5)) * WW + xb + (pix & 31);
        fxv[p] = fbp[hw];                 // coalesced
        fyv[p] = fbp[HW + hw];
    }
    asm volatile("" ::: "memory");        // pin: flow loads precede all gll

    // ---- pre-issue staging for groups 0..2 (all three buffers) ----
    STAGE(0, 0);
    STAGE(1, 1);
    STAGE(2, 2);

    // ---- per-pixel precompute (register-only; hides staging latency) ----
    // Compiler's wait for fxv/fyv is vmcnt(12): drains flow only, not gll.
    float w00[NPX], w01[NPX], w10[NPX], w11[NPX];
    int   lidx[NPX], dxv[NPX], dyov[NPX], obase[NPX];
    int   fbmask = 0;

#pragma unroll
    for (int p = 0; p < NPX; ++p) {
        const int pix = p * 256 + t;      // 0..1023 within tile
        const int row = pix >> 5;
        const int col = pix & 31;
        const int h   = yb + row;
        const int w   = xb + col;
        obase[p] = h * WW + w;

        const float gx = (float)w + fxv[p];
        const float gy = (float)h + fyv[p];

        const float x0f = floorf(gx), y0f = floorf(gy);
        const float wx1 = gx - x0f, wx0 = 1.0f - wx1;
        const float wy1 = gy - y0f, wy0 = 1.0f - wy1;

        const bool vx0 = (x0f >= 0.0f)        && (x0f <= (float)(WW - 1));
        const bool vx1 = (x0f + 1.0f >= 0.0f) && (x0f + 1.0f <= (float)(WW - 1));
        const bool vy0 = (y0f >= 0.0f)        && (y0f <= (float)(HH - 1));
        const bool vy1 = (y0f + 1.0f >= 0.0f) && (y0f + 1.0f <= (float)(HH - 1));

        float a00 = wx0 * wy0 * ((vx0 && vy0) ? 1.0f : 0.0f);
        float a01 = wx1 * wy0 * ((vx1 && vy0) ? 1.0f : 0.0f);
        float a10 = wx0 * wy1 * ((vx0 && vy1) ? 1.0f : 0.0f);
        float a11 = wx1 * wy1 * ((vx1 && vy1) ? 1.0f : 0.0f);

        const float msum = a00 + a01 + a10 + a11;
        const float mask = (msum < 0.9999f) ? 0.0f : 1.0f;
        w00[p] = a00 * mask; w01[p] = a01 * mask;
        w10[p] = a10 * mask; w11[p] = a11 * mask;

        const int x0 = min(max((int)x0f, 0), WW - 1);
        const int x1 = min(max((int)x0f + 1, 0), WW - 1);
        const int y0 = min(max((int)y0f, 0), HH - 1);
        const int y1 = min(max((int)y0f + 1, 0), HH - 1);

        const int dx = x1 - x0;           // 0 or 1
        const int dy = y1 - y0;
        dxv[p]  = dx;
        dyov[p] = dy * REGE;

        const int xl = x0 - x0r;          // region-local (may be out of range)
        const int yl = y0 - y0r;
        if (!((xl >= 0) && (xl + dx <= REGE - 1) &&
              (yl >= 0) && (yl + dy <= REGE - 1)))
            fbmask |= (1 << p);
        // Clamp to [0, REGE-2]: exact for every in-region pixel, safe-finite
        // for fallback pixels (overwritten by fixup).
        lidx[p] = min(max(yl, 0), REGE - 2) * REGE + min(max(xl, 0), REGE - 2);
    }

    float res[CH][NPX];                   // register output accumulator

    // ---- prologue handoff: retire S0 only (S1,S2 stay in flight) ----
    WAITVM(8);
    BAR();

    // ---- 16 phases, counted vmcnt, never a full drain ----
    PHASE(0);   PHASE(1);   PHASE(2);   PHASE(3);
    PHASE(4);   PHASE(5);   PHASE(6);   PHASE(7);
    PHASE(8);   PHASE(9);   PHASE(10);  PHASE(11);
    PHASE(12);
    // g=13: no STAGE(16); queue=[S14,S15] -> wait(4) retires S14.
    GATHER(13, 1);  WAITVM(4);  BAR();
    // g=14: queue=[S15] -> wait(0) retires S15.
    GATHER(14, 2);  WAITVM(0);  BAR();
    GATHER(15, 0);                        // last group: nothing in flight

    // ---- bulk store: coalesced per channel ----
#pragma unroll
    for (int c = 0; c < CH; ++c) {
        float* o0 = out + ib + (size_t)c * HW;
#pragma unroll
        for (int p = 0; p < NPX; ++p)
            o0[obase[p]] = res[c][p];
    }

    // ---- fixup: redo fallback pixels from global (all 16 channels) ----
    // Rare path (~1-2% of pixels). Recomputes weights/indices from a flow
    // reload (L2-hot).
    if (fbmask) {
#pragma unroll
        for (int p = 0; p < NPX; ++p) {
            if (!(fbmask & (1 << p))) continue;
            const int pix = p * 256 + t;
            const int row = pix >> 5;
            const int col = pix & 31;
            const int h   = yb + row;
            const int w   = xb + col;
            const int hw  = h * WW + w;

            const float gx = (float)w + fxv[p];
            const float gy = (float)h + fyv[p];

            const float x0f = floorf(gx), y0f = floorf(gy);
            const float wx1 = gx - x0f, wx0 = 1.0f - wx1;
            const float wy1 = gy - y0f, wy0 = 1.0f - wy1;

            const bool vx0 = (x0f >= 0.0f)        && (x0f <= (float)(WW - 1));
            const bool vx1 = (x0f + 1.0f >= 0.0f) && (x0f + 1.0f <= (float)(WW - 1));
            const bool vy0 = (y0f >= 0.0f)        && (y0f <= (float)(HH - 1));
            const bool vy1 = (y0f + 1.0f >= 0.0f) && (y0f + 1.0f <= (float)(HH - 1));

            float a00 = wx0 * wy0 * ((vx0 && vy0) ? 1.0f : 0.0f);
            float a01 = wx1 * wy0 * ((vx1 && vy0) ? 1.0f : 0.0f);
            float a10 = wx0 * wy1 * ((vx0 && vy1) ? 1.0f : 0.0f);
            float a11 = wx1 * wy1 * ((vx1 && vy1) ? 1.0f : 0.0f);

            const float msum = a00 + a01 + a10 + a11;
            const float mask = (msum < 0.9999f) ? 0.0f : 1.0f;
            a00 *= mask; a01 *= mask; a10 *= mask; a11 *= mask;

            const int x0 = min(max((int)x0f, 0), WW - 1);
            const int x1 = min(max((int)x0f + 1, 0), WW - 1);
            const int y0 = min(max((int)y0f, 0), HH - 1);
            const int y1 = min(max((int)y0f + 1, 0), HH - 1);

            const int gA  = y0 * WW + x0;
            const int dx  = x1 - x0;
            const int dyo = (y1 - y0) * WW;

            const float* ic = img + ib;
            float*       oc = out + ib + hw;
            for (int c = 0; c < CH; ++c) {
                const float* pc = ic + (size_t)c * HW;
                const float v = a00 * pc[gA]
                              + a01 * pc[gA + dx]
                              + a10 * pc[gA + dyo]
                              + a11 * pc[gA + dx + dyo];
                oc[(size_t)c * HW] = v;
            }
        }
    }
}

extern "C" void kernel_launch(void* const* d_in, const int* in_sizes, int n_in,
                              void* d_out, int out_size, void* d_ws, size_t ws_size,
                              hipStream_t stream) {
    const float* img = (const float*)d_in[0];  // [8,16,512,512] fp32
    const float* flo = (const float*)d_in[1];  // [8,2,512,512] fp32
    float* out = (float*)d_out;                // [8,16,512,512] fp32

    const int blocks = BATCH * (HH / TILE) * (WW / TILE);  // 2048
    warp_cnt<<<blocks, 256, 0, stream>>>(img, flo, out);
}